// Round 22
// baseline (101.229 us; speedup 1.0000x reference)
//
#include <hip/hip_runtime.h>

#define B_   4
#define C_   256
#define CR_  64
#define H_   128
#define W_   128
#define HW_  (H_ * W_)
#define G_   16
#define GC_  16
#define KO_  144   // K*K*G = 9*16
#define EPS_ 1e-5f

typedef __bf16 bf16x8 __attribute__((ext_vector_type(8)));
typedef __bf16 bf16x4 __attribute__((ext_vector_type(4)));
typedef float  f32x4  __attribute__((ext_vector_type(4)));

#define ST 36   // bf16 row stride (x4 aligned; 18-dword rows spread banks)

// ---------------------------------------------------------------------------
// prep: build MFMA A-fragments (lane order: m = lane&15, kslot = 8*(lane>>4)+j;
// the kslot permutation cancels between A and B since both use it).
// ---------------------------------------------------------------------------
__global__ void prep_kernel(const float* __restrict__ w1,
                            const float* __restrict__ gamma,
                            const float* __restrict__ beta,
                            const float* __restrict__ mean,
                            const float* __restrict__ var,
                            const float* __restrict__ w2,
                            __bf16* __restrict__ w1frag,
                            __bf16* __restrict__ w2frag,
                            float* __restrict__ bias2) {
    int idx = blockIdx.x * 256 + threadIdx.x;
    if (idx < 16384) {                      // w1frag: [8 kc][4 mt][64 l][8 j]
        int kc = idx >> 11, r = idx & 2047;
        int mt = r >> 9, l = (r >> 3) & 63, j = r & 7;
        int o = mt * 16 + (l & 15);
        int c = kc * 32 + 8 * (l >> 4) + j;
        float alpha = gamma[o] * rsqrtf(var[o] + EPS_);
        w1frag[idx] = (__bf16)(w1[o * C_ + c] * alpha);
        if (idx < CR_) {
            float a2 = gamma[idx] * rsqrtf(var[idx] + EPS_);
            bias2[idx] = beta[idx] - mean[idx] * a2;
        }
    } else if (idx < 16384 + 9216) {        // w2frag: [9 mt][2 kc2][64 l][8 j]
        int i2 = idx - 16384;
        int mt = i2 >> 10, r = i2 & 1023;
        int kc2 = r >> 9, l = (r >> 3) & 63, j = r & 7;
        int o2 = mt * 16 + (l & 15);
        int cc = kc2 * 32 + 8 * (l >> 4) + j;
        w2frag[i2] = (__bf16)(w2[o2 * CR_ + cc]);
    }
}

// ---------------------------------------------------------------------------
// FULLY FUSED v5: 32-px tiles for occupancy. Block = (b, h, quarter-row),
// 256 threads (4 waves), grid 2048 (XCD-swizzled) -> 8192 waves supplied.
// Phase 1: h1[64][32] via MFMA (wave = M-tile wm, 2 N-tiles).
// Phase 2: wk[144][32] -> LDS bf16; wave = (mt-half, nt); barrier before
//          wkbuf stores (wkbuf overlays hbuf).
// Phase 3: barrier-free: thread = (q8 quad, cp -> 8 ch of group cp>>1);
//          wk4 hoisted once; 2-deep pipeline; shfl interior edges; guarded
//          scalar loads for tile-boundary lanes; NT out stores.
// LDS: max(xs 4.6K + hbuf 4.6K, wkbuf 10.4K) = 10368 B.
// ---------------------------------------------------------------------------
__global__ __launch_bounds__(256, 6) void fused_kernel(
        const float* __restrict__ x,
        const __bf16* __restrict__ w1frag,
        const float* __restrict__ bias2,
        const __bf16* __restrict__ w2frag,
        const float* __restrict__ b2,
        float* __restrict__ out) {
    __shared__ __align__(16) char smem[10368];
    __bf16* xs    = (__bf16*)smem;                  // [2][32][ST] = 4608 B
    __bf16* hbuf  = (__bf16*)(smem + 4608);         // [64][ST]    = 4608 B
    __bf16* wkbuf = (__bf16*)smem;                  // [144][ST]   = 10368 B (phase 2+3)

    const int tid  = threadIdx.x;
    const int lane = tid & 63;
    const int wave = tid >> 6;            // 0..3
    const int g = lane >> 4, n = lane & 15;

    // XCD-chunked bijective swizzle: 2048 = 8 XCD x 256 consecutive tiles
    const int bid = (blockIdx.x & 7) * 256 + (blockIdx.x >> 3);
    const int b   = bid >> 9;             // 0..3
    const int rem = bid & 511;
    const int h   = rem >> 2;             // 0..127
    const int qt  = rem & 3;              // quarter-row 0..3
    const int w0g = qt * 32;

    const float* xrow = x + (size_t)b * C_ * HW_ + h * W_ + w0g;
    const int cl  = tid >> 3;             // 0..31 (staging channel)
    const int f4i = tid & 7;              // 0..7  (staging float4 col)

    // ---- stage chunk 0 (32 ch x 32 px of row tile) into xs buf 0 ----
    {
        float4 v = *(const float4*)&xrow[(size_t)cl * HW_ + f4i * 4];
        *(bf16x4*)&xs[cl * ST + f4i * 4] =
            bf16x4{(__bf16)v.x, (__bf16)v.y, (__bf16)v.z, (__bf16)v.w};
    }
    __syncthreads();

    // ======================= phase 1: conv1 ============================
    f32x4 acc1[2];
    acc1[0] = f32x4{0.f, 0.f, 0.f, 0.f};
    acc1[1] = f32x4{0.f, 0.f, 0.f, 0.f};

    for (int kc = 0; kc < 8; ++kc) {
        const int buf = kc & 1;
        float4 nf;
        if (kc < 7)
            nf = *(const float4*)&xrow[(size_t)(32 * (kc + 1) + cl) * HW_ + f4i * 4];
        bf16x8 a = *(const bf16x8*)&w1frag[((kc * 4 + wave) * 64 + lane) * 8];
        const int base = buf * (32 * ST);
        bf16x8 bt[2];
#pragma unroll
        for (int t = 0; t < 2; ++t)
#pragma unroll
            for (int j = 0; j < 8; ++j)
                bt[t][j] = xs[base + (8 * g + j) * ST + t * 16 + n];
        acc1[0] = __builtin_amdgcn_mfma_f32_16x16x32_bf16(a, bt[0], acc1[0], 0, 0, 0);
        acc1[1] = __builtin_amdgcn_mfma_f32_16x16x32_bf16(a, bt[1], acc1[1], 0, 0, 0);
        if (kc < 7) {
            const int nb = (buf ^ 1) * (32 * ST);
            *(bf16x4*)&xs[nb + cl * ST + f4i * 4] =
                bf16x4{(__bf16)nf.x, (__bf16)nf.y, (__bf16)nf.z, (__bf16)nf.w};
        }
        __syncthreads();
    }

    // bias + relu -> hbuf (bf16). D elem: o = wave*16+4g+j, px = t*16+n
    {
        const int Mo = wave * 16 + 4 * g;
        float4 bv = *(const float4*)&bias2[Mo];
        float bj[4] = {bv.x, bv.y, bv.z, bv.w};
#pragma unroll
        for (int t = 0; t < 2; ++t)
#pragma unroll
            for (int j = 0; j < 4; ++j)
                hbuf[(Mo + j) * ST + t * 16 + n] = (__bf16)fmaxf(acc1[t][j] + bj[j], 0.f);
    }
    __syncthreads();

    // ======================= phase 2: conv2 ============================
    const int nt = wave & 1;              // N-tile 0..1
    const int mh = wave >> 1;             // mt half: 0 -> mt 0..4, 1 -> mt 5..8
    const int nmt = mh ? 4 : 5;
    const int mt0 = mh ? 5 : 0;

    f32x4 acc2[5];
#pragma unroll
    for (int m = 0; m < 5; ++m) acc2[m] = f32x4{0.f, 0.f, 0.f, 0.f};

#pragma unroll
    for (int kc2 = 0; kc2 < 2; ++kc2) {
        bf16x8 hb;
#pragma unroll
        for (int j = 0; j < 8; ++j)
            hb[j] = hbuf[(kc2 * 32 + 8 * g + j) * ST + nt * 16 + n];
        for (int im = 0; im < nmt; ++im) {
            bf16x8 a = *(const bf16x8*)&w2frag[(((mt0 + im) * 2 + kc2) * 64 + lane) * 8];
            acc2[im] = __builtin_amdgcn_mfma_f32_16x16x32_bf16(a, hb, acc2[im], 0, 0, 0);
        }
    }
    __syncthreads();   // all hbuf reads done -> wkbuf may overlay it

    for (int im = 0; im < nmt; ++im) {
        const int o0 = (mt0 + im) * 16 + 4 * g;
        float4 bv = *(const float4*)&b2[o0];
        float bj[4] = {bv.x, bv.y, bv.z, bv.w};
#pragma unroll
        for (int j = 0; j < 4; ++j)
            wkbuf[(o0 + j) * ST + nt * 16 + n] = (__bf16)(acc2[im][j] + bj[j]);
    }
    __syncthreads();   // wkbuf visible; LAST barrier

    // ======================= phase 3: involution (barrier-free) =========
    const int q8 = tid & 7;               // px quad within 32: w0 = q8*4
    const int cp = tid >> 3;              // 0..31 -> 8 channels each
    const int gq = cp >> 1;               // group (constant per thread)
    const int w0 = q8 * 4;
    const bool lb = (q8 == 0), rb = (q8 == 7);
    const bool il = (qt == 0), ir = (qt == 3);      // image edges
    const bool h0ok = (h > 0), h2ok = (h < H_ - 1);

    // hoist 9 wk taps once (reused over all 8 channels)
    float4 wk4[9];
#pragma unroll
    for (int k = 0; k < 9; ++k) {
        bf16x4 v = *(const bf16x4*)&wkbuf[(gq * 9 + k) * ST + w0];
        wk4[k] = float4{(float)v[0], (float)v[1], (float)v[2], (float)v[3]};
    }

    const int ch0 = cp * 8;
    float4 bufA[3], bufB[3];
    float  eA[3], eB[3];                  // union: left-edge (q8==0) or right (q8==7)

    auto LOADCH = [&](int ci, float4* bf, float* e) {
        const float* xc = x + ((size_t)(b * C_ + ch0 + ci)) * HW_ + (h - 1) * W_ + w0g + w0;
#pragma unroll
        for (int dr = 0; dr < 3; ++dr) {
            const bool ok = (dr == 0) ? h0ok : (dr == 2) ? h2ok : true;
            const float* rp = xc + dr * W_;
            bf[dr] = ok ? *(const float4*)rp : float4{0.f, 0.f, 0.f, 0.f};
            e[dr] = 0.f;
            if (lb && ok && !il) e[dr] = rp[-1];
            if (rb && ok && !ir) e[dr] = rp[4];
        }
    };

    LOADCH(0, bufA, eA);
#pragma unroll
    for (int p = 0; p < 8; ++p) {
        float4* cur = (p & 1) ? bufB : bufA;
        float*  ecur = (p & 1) ? eB : eA;
        if (p < 7) {
            if (p & 1) LOADCH(p + 1, bufA, eA);
            else       LOADCH(p + 1, bufB, eB);
        }
        float4 acc = {0.f, 0.f, 0.f, 0.f};
#pragma unroll
        for (int dr = 0; dr < 3; ++dr) {
            float4 c = cur[dr];
            float lms = __shfl(c.w, lane - 1);
            float rms = __shfl(c.x, lane + 1);
            float lm = lb ? ecur[dr] : lms;
            float rm = rb ? ecur[dr] : rms;
            float4 t0 = wk4[3 * dr + 0];
            float4 t1 = wk4[3 * dr + 1];
            float4 t2 = wk4[3 * dr + 2];
            acc.x = fmaf(t0.x, lm,  acc.x);
            acc.y = fmaf(t0.y, c.x, acc.y);
            acc.z = fmaf(t0.z, c.y, acc.z);
            acc.w = fmaf(t0.w, c.z, acc.w);
            acc.x = fmaf(t1.x, c.x, acc.x);
            acc.y = fmaf(t1.y, c.y, acc.y);
            acc.z = fmaf(t1.z, c.z, acc.z);
            acc.w = fmaf(t1.w, c.w, acc.w);
            acc.x = fmaf(t2.x, c.y, acc.x);
            acc.y = fmaf(t2.y, c.z, acc.y);
            acc.z = fmaf(t2.z, c.w, acc.z);
            acc.w = fmaf(t2.w, rm,  acc.w);
        }
        f32x4 av = {acc.x, acc.y, acc.z, acc.w};
        __builtin_nontemporal_store(av,
            (f32x4*)&out[((size_t)(b * C_ + ch0 + p)) * HW_ + h * W_ + w0g + w0]);
    }
}

// ---------------------------------------------------------------------------
extern "C" void kernel_launch(void* const* d_in, const int* in_sizes, int n_in,
                              void* d_out, int out_size, void* d_ws, size_t ws_size,
                              hipStream_t stream) {
    const float* x     = (const float*)d_in[0];
    const float* w1    = (const float*)d_in[1];
    const float* gamma = (const float*)d_in[2];
    const float* beta  = (const float*)d_in[3];
    const float* mean  = (const float*)d_in[4];
    const float* var   = (const float*)d_in[5];
    const float* w2    = (const float*)d_in[6];
    const float* b2    = (const float*)d_in[7];
    float* out = (float*)d_out;

    char* ws = (char*)d_ws;
    __bf16* w1frag = (__bf16*)(ws);                 // 32 KB [8][4][64][8]
    __bf16* w2frag = (__bf16*)(ws + (32 << 10));    // 18 KB [9][2][64][8]
    float*  bias2  = (float*)(ws + (56 << 10));     // 256 B

    hipLaunchKernelGGL(prep_kernel, dim3(100), dim3(256), 0, stream,
                       w1, gamma, beta, mean, var, w2, w1frag, w2frag, bias2);
    hipLaunchKernelGGL(fused_kernel, dim3(2048), dim3(256), 0, stream,
                       x, w1frag, bias2, w2frag, b2, out);
}